// Round 1
// baseline (448.259 us; speedup 1.0000x reference)
//
#include <hip/hip_runtime.h>
#include <hip/hip_bf16.h>
#include <stdint.h>

// Int8Linear: per-row symmetric int8 quant (w per-output-channel, x per-token),
// int8 GEMM (exact int32 accum via MFMA i8), fused dequant + bf16 bias epilogue.
// M=8192, K=4096, N=4096 for this problem instance.
//
// R4 changes vs R3:
//  - quant: block-per-row (2 barriers, 4 loads/lane, 16 IEEE fdiv/lane) ->
//    wave-per-row (barrier-free, 16 float4 loads/lane register-resident,
//    shuffle-only reduce, one rcp per row + multiplies). Quant was ~half the
//    total runtime at ~1.1 TB/s; this removes the load->barrier->div->store
//    serialization that was starving the memory pipe.
//  - gemm: byte-identical to R3 (8-phase schedule port is the next step).

using i32x4  = __attribute__((ext_vector_type(4))) int;
using i32x16 = __attribute__((ext_vector_type(16))) int;

#define TILE 128
#define BK 64   // int8 elements of K per LDS stage

// ---------------------------------------------------------------------------
// Fused per-row quantization for both W [N,K] and X [M,K]; one WAVE per row.
// wave w < nw does weight row w, else x row w-nw. K=4096: 64 lanes x 16 float4.
// scale = max(absmax/127, 1e-12); q = clip(rint(v/scale), -128, 127).
// (rint(v * (1/scale)) used; tie flips are ~3e-5/elem and perturb outputs by
//  <= xs*ws*127 ~ 2e-3, far below tolerance.)
// ---------------------------------------------------------------------------
__global__ __launch_bounds__(256) void quant_rows_wave(
    const float* __restrict__ w_in, const float* __restrict__ x_in,
    int8_t* __restrict__ w_q, int8_t* __restrict__ x_q,
    float* __restrict__ w_s, float* __restrict__ x_s,
    int nw, int nrows, int K)
{
    const int wave_id = (int)((blockIdx.x * (unsigned)blockDim.x + threadIdx.x) >> 6);
    if (wave_id >= nrows) return;
    const int lane = threadIdx.x & 63;

    const bool is_w = (wave_id < nw);
    const int row = is_w ? wave_id : (wave_id - nw);
    const float* r = (is_w ? w_in : x_in) + (size_t)row * K;
    int8_t* qout   = (is_w ? w_q : x_q) + (size_t)row * K;
    float* scales  = is_w ? w_s : x_s;

    // 16 outstanding 16B loads per lane; lane-consecutive 16B chunks per i.
    float4 v[16];
#pragma unroll
    for (int i = 0; i < 16; ++i)
        v[i] = *(const float4*)(r + i * 256 + lane * 4);

    float amax = 0.f;
#pragma unroll
    for (int i = 0; i < 16; ++i) {
        amax = fmaxf(amax, fmaxf(fmaxf(fabsf(v[i].x), fabsf(v[i].y)),
                                 fmaxf(fabsf(v[i].z), fabsf(v[i].w))));
    }

    // wave-level butterfly reduce, no LDS, no barriers
#pragma unroll
    for (int off = 32; off >= 1; off >>= 1)
        amax = fmaxf(amax, __shfl_xor(amax, off));

    const float scale = fmaxf(amax / 127.0f, 1e-12f);   // exact, once per row
    if (lane == 0) scales[row] = scale;
    const float inv = 1.0f / scale;                     // once per row

#pragma unroll
    for (int i = 0; i < 16; ++i) {
        float q0 = fminf(fmaxf(rintf(v[i].x * inv), -128.f), 127.f);
        float q1 = fminf(fmaxf(rintf(v[i].y * inv), -128.f), 127.f);
        float q2 = fminf(fmaxf(rintf(v[i].z * inv), -128.f), 127.f);
        float q3 = fminf(fmaxf(rintf(v[i].w * inv), -128.f), 127.f);
        union { signed char c[4]; int i32; } u;
        u.c[0] = (signed char)(int)q0;
        u.c[1] = (signed char)(int)q1;
        u.c[2] = (signed char)(int)q2;
        u.c[3] = (signed char)(int)q3;
        *(int*)(qout + i * 256 + lane * 4) = u.i32;     // coalesced 256B/wave
    }
}

// ---------------------------------------------------------------------------
// int8 GEMM: C[M][N] = A[M][K] . B[N][K]^T, int32 accum, fused dequant.
// 128x128 tile, BK=64, 4 waves (2x2, 64x64 each), global_load_lds width=16,
// 32x32x32 i8 MFMA, 2x2 MFMA tiles per wave.
//
// LDS swizzle (R2, verified conflict-free): physical 16B chunk c of row r
// holds logical k-chunk (c - (r>>1)) & 3; staged by permuting the global
// source chunk per thread. Readers: phys = (logical + (r>>1)) & 3.
//
// 32x32x32 i8 layouts:
//   A: m = lane&31, k = (lane>>5)*16 + j   (16 i8 per lane = i32x4)
//   B: n = lane&31, k = (lane>>5)*16 + j
//   C/D: col = lane&31, row = (reg&3) + 8*(reg>>2) + 4*(lane>>5)  [m74/m101]
// ---------------------------------------------------------------------------
__global__ __launch_bounds__(256) void gemm_i8_kernel(
    const int8_t* __restrict__ A,   // [M][K] x_i8
    const int8_t* __restrict__ B,   // [N][K] w_i8
    const float*  __restrict__ xs,  // [M] x scales
    const float*  __restrict__ ws,  // [N] w scales
    const float*  __restrict__ bias,// [N] fp32 bias
    float*        __restrict__ out, // [M][N] fp32
    int M, int N, int K)
{
    __shared__ int8_t sA[TILE * BK];   // [128 rows][64 bytes]
    __shared__ int8_t sB[TILE * BK];

    const int tid   = threadIdx.x;
    const int wave  = tid >> 6;
    const int lane  = tid & 63;
    const int l31   = lane & 31;
    const int lhalf = lane >> 5;       // 0/1

    const int bm = blockIdx.y * TILE;
    const int bn = blockIdx.x * TILE;
    const int wm = (wave >> 1) * 64;
    const int wn = (wave & 1) * 64;

    i32x16 acc[2][2];
#pragma unroll
    for (int i = 0; i < 2; ++i)
#pragma unroll
        for (int j = 0; j < 2; ++j)
#pragma unroll
            for (int r = 0; r < 16; ++r) acc[i][j][r] = 0;

    // staging: thread t -> LDS offset t*16 (physical row t>>2, chunk t&3).
    // source chunk g = ((t&3) - (t>>3)) & 3 implements the swizzle.
    const int srow = tid >> 2;
    const int g    = ((tid & 3) - ((tid >> 3) & 3)) & 3;
    const int soff = g * 16;

    const int8_t* aptr0 = A + (size_t)(bm + srow) * K + soff;
    const int8_t* aptr1 = A + (size_t)(bm + 64 + srow) * K + soff;
    const int8_t* bptr0 = B + (size_t)(bn + srow) * K + soff;
    const int8_t* bptr1 = B + (size_t)(bn + 64 + srow) * K + soff;

    int8_t* sA0 = sA + tid * 16;
    int8_t* sA1 = sA + 4096 + tid * 16;
    int8_t* sB0 = sB + tid * 16;
    int8_t* sB1 = sB + 4096 + tid * 16;

    // fragment-read physical chunks: logical chunk = lhalf + khalf*2,
    // row parity term = (l31>>1) (wm, it*32 are 0 mod 8 after >>1, drop out)
    const int pc0 = ((lhalf + 0 + (l31 >> 1)) & 3) * 16;   // khalf=0
    const int pc1 = ((lhalf + 2 + (l31 >> 1)) & 3) * 16;   // khalf=1

    for (int k0 = 0; k0 < K; k0 += BK) {
        __syncthreads();
        __builtin_amdgcn_global_load_lds(
            (const __attribute__((address_space(1))) void*)(aptr0 + k0),
            (__attribute__((address_space(3))) void*)sA0, 16, 0, 0);
        __builtin_amdgcn_global_load_lds(
            (const __attribute__((address_space(1))) void*)(aptr1 + k0),
            (__attribute__((address_space(3))) void*)sA1, 16, 0, 0);
        __builtin_amdgcn_global_load_lds(
            (const __attribute__((address_space(1))) void*)(bptr0 + k0),
            (__attribute__((address_space(3))) void*)sB0, 16, 0, 0);
        __builtin_amdgcn_global_load_lds(
            (const __attribute__((address_space(1))) void*)(bptr1 + k0),
            (__attribute__((address_space(3))) void*)sB1, 16, 0, 0);
        __syncthreads();

        i32x4 af[2][2], bf[2][2];   // [it or jt][khalf]
#pragma unroll
        for (int it = 0; it < 2; ++it) {
            const int arow = (wm + it * 32 + l31) * BK;
            af[it][0] = *(const i32x4*)(sA + arow + pc0);
            af[it][1] = *(const i32x4*)(sA + arow + pc1);
        }
#pragma unroll
        for (int jt = 0; jt < 2; ++jt) {
            const int brow = (wn + jt * 32 + l31) * BK;
            bf[jt][0] = *(const i32x4*)(sB + brow + pc0);
            bf[jt][1] = *(const i32x4*)(sB + brow + pc1);
        }

#pragma unroll
        for (int kh = 0; kh < 2; ++kh)
#pragma unroll
            for (int it = 0; it < 2; ++it)
#pragma unroll
                for (int jt = 0; jt < 2; ++jt)
                    acc[it][jt] = __builtin_amdgcn_mfma_i32_32x32x32_i8(
                        af[it][kh], bf[jt][kh], acc[it][jt], 0, 0, 0);
    }

    // Epilogue: out = fp32( bf16( bf16(acc*xs*ws) + bf16(bias) ) )
    // C/D: col = lane&31, row = (reg&3) + 8*(reg>>2) + 4*(lane>>5)
#pragma unroll
    for (int jt = 0; jt < 2; ++jt) {
        const int col = bn + wn + jt * 32 + l31;
        const float wsv = ws[col];
        const float bsv = __bfloat162float(__float2bfloat16(bias[col]));
#pragma unroll
        for (int it = 0; it < 2; ++it) {
            const int rowbase = bm + wm + it * 32 + 4 * lhalf;
#pragma unroll
            for (int r = 0; r < 16; ++r) {
                const int row = rowbase + (r & 3) + 8 * (r >> 2);
                const float v = (float)acc[it][jt][r] * xs[row] * wsv;
                const float vb = __bfloat162float(__float2bfloat16(v));
                const float res = __bfloat162float(__float2bfloat16(vb + bsv));
                out[(size_t)row * N + col] = res;
            }
        }
    }
}

// ---------------------------------------------------------------------------
extern "C" void kernel_launch(void* const* d_in, const int* in_sizes, int n_in,
                              void* d_out, int out_size, void* d_ws, size_t ws_size,
                              hipStream_t stream)
{
    const float* x    = (const float*)d_in[0];   // [B,S,K] fp32
    const float* wfp  = (const float*)d_in[1];   // [N,K] fp32
    const float* bias = (const float*)d_in[2];   // [N] fp32
    float* out = (float*)d_out;                  // [M,N] fp32

    const int N = in_sizes[2];
    const int K = in_sizes[1] / N;
    const int M = in_sizes[0] / K;

    // workspace layout: w_i8[N*K] | x_i8[M*K] | w_scales[N] | x_scales[M]
    int8_t* w_i8 = (int8_t*)d_ws;
    int8_t* x_i8 = w_i8 + (size_t)N * K;
    float* w_scales = (float*)(x_i8 + (size_t)M * K);
    float* x_scales = w_scales + N;

    const int nrows = N + M;                     // one wave per row
    const int nblocks = (nrows + 3) / 4;         // 4 waves / 256-thread block
    quant_rows_wave<<<nblocks, 256, 0, stream>>>(wfp, x, w_i8, x_i8,
                                                 w_scales, x_scales,
                                                 N, nrows, K);

    dim3 grid(N / TILE, M / TILE);
    gemm_i8_kernel<<<grid, 256, 0, stream>>>(x_i8, w_i8, x_scales, w_scales,
                                             bias, out, M, N, K);
}

// Round 2
// 432.902 us; speedup vs baseline: 1.0355x; 1.0355x over previous
//
#include <hip/hip_runtime.h>
#include <hip/hip_bf16.h>
#include <stdint.h>

// Int8Linear: per-row symmetric int8 quant (w per-output-channel, x per-token),
// int8 GEMM (exact int32 accum via MFMA i8), fused dequant + bf16 bias epilogue.
// M=8192, K=4096, N=4096 for this problem instance.
//
// R5 changes vs R4:
//  - gemm rewritten: 128x128/BK=64 serial 2-barrier loop -> 256x256/BK=128,
//    8 waves, double-buffered LDS with prefetch-overlap (stage t+1 issued in
//    phases 0-1 of tile t; ONE vmcnt(0)+s_barrier per K-tile instead of a
//    full drain around every stage). XOR chunk swizzle (phys = log ^ (row&7))
//    with inverse-permuted global source + linear global_load_lds dest.
//  - quant: unchanged from R4 (wave-per-row).

using i32x4  = __attribute__((ext_vector_type(4))) int;
using i32x16 = __attribute__((ext_vector_type(16))) int;

#define BM 256
#define BN 256
#define BKB 128   // K-bytes (= int8 k-elems) per LDS tile

// ---------------------------------------------------------------------------
// Fused per-row quantization for both W [N,K] and X [M,K]; one WAVE per row.
// ---------------------------------------------------------------------------
__global__ __launch_bounds__(256) void quant_rows_wave(
    const float* __restrict__ w_in, const float* __restrict__ x_in,
    int8_t* __restrict__ w_q, int8_t* __restrict__ x_q,
    float* __restrict__ w_s, float* __restrict__ x_s,
    int nw, int nrows, int K)
{
    const int wave_id = (int)((blockIdx.x * (unsigned)blockDim.x + threadIdx.x) >> 6);
    if (wave_id >= nrows) return;
    const int lane = threadIdx.x & 63;

    const bool is_w = (wave_id < nw);
    const int row = is_w ? wave_id : (wave_id - nw);
    const float* r = (is_w ? w_in : x_in) + (size_t)row * K;
    int8_t* qout   = (is_w ? w_q : x_q) + (size_t)row * K;
    float* scales  = is_w ? w_s : x_s;

    float4 v[16];
#pragma unroll
    for (int i = 0; i < 16; ++i)
        v[i] = *(const float4*)(r + i * 256 + lane * 4);

    float amax = 0.f;
#pragma unroll
    for (int i = 0; i < 16; ++i) {
        amax = fmaxf(amax, fmaxf(fmaxf(fabsf(v[i].x), fabsf(v[i].y)),
                                 fmaxf(fabsf(v[i].z), fabsf(v[i].w))));
    }

#pragma unroll
    for (int off = 32; off >= 1; off >>= 1)
        amax = fmaxf(amax, __shfl_xor(amax, off));

    const float scale = fmaxf(amax / 127.0f, 1e-12f);
    if (lane == 0) scales[row] = scale;
    const float inv = 1.0f / scale;

#pragma unroll
    for (int i = 0; i < 16; ++i) {
        float q0 = fminf(fmaxf(rintf(v[i].x * inv), -128.f), 127.f);
        float q1 = fminf(fmaxf(rintf(v[i].y * inv), -128.f), 127.f);
        float q2 = fminf(fmaxf(rintf(v[i].z * inv), -128.f), 127.f);
        float q3 = fminf(fmaxf(rintf(v[i].w * inv), -128.f), 127.f);
        union { signed char c[4]; int i32; } u;
        u.c[0] = (signed char)(int)q0;
        u.c[1] = (signed char)(int)q1;
        u.c[2] = (signed char)(int)q2;
        u.c[3] = (signed char)(int)q3;
        *(int*)(qout + i * 256 + lane * 4) = u.i32;
    }
}

// ---------------------------------------------------------------------------
// int8 GEMM: C[M][N] = A[M][K] . B[N][K]^T, int32 accum, fused dequant.
// 256x256 tile, BK=128 i8 (128B rows), 8 waves (2M x 4N, 128x64 each),
// 32x32x32 i8 MFMA, double-buffered LDS with prefetch overlap.
//
// LDS layout: row-major [256 rows][128 B], 16B chunks swizzled:
//   phys_chunk = log_chunk ^ (row & 7)
// Staged via global_load_lds (linear dest: byte = (l*512 + tid)*16, i.e.
// row = l*64 + tid/8, phys_chunk = tid&7) with the INVERSE permutation
// applied to the per-thread global source chunk:
//   log_chunk = (tid&7) ^ ((tid>>3)&7)   (l*64 = 0 mod 8 drops out).
//
// Frag reads (32x32x32 i8): lane reads 16B at row = base + (lane&31),
//   log_chunk = ks*2 + (lane>>5), phys = log_chunk ^ (row&7).
// C/D: col = lane&31, row = (reg&3) + 8*(reg>>2) + 4*(lane>>5)  [m74/m101]
//
// Sync: ONE [s_waitcnt vmcnt(0); s_barrier] per K-tile. Within a tile all
// waves read buf[cur] and stage into buf[cur^1] only (no aliasing). Stage
// loads are issued in phases 0-1 so they fly under phases' MFMA before the
// tile-end drain. Raw barrier + asm memory clobbers (NOT __syncthreads,
// which would drain vmcnt at every use).
// ---------------------------------------------------------------------------
__global__ __launch_bounds__(512, 2) void gemm_i8_256(
    const int8_t* __restrict__ A,   // [M][K] x_i8
    const int8_t* __restrict__ B,   // [N][K] w_i8
    const float*  __restrict__ xs,  // [M]
    const float*  __restrict__ ws,  // [N]
    const float*  __restrict__ bias,// [N]
    float*        __restrict__ out, // [M][N] fp32
    int M, int N, int K)
{
    __shared__ int8_t sA[2][BM * BKB];   // 2 x 32 KiB
    __shared__ int8_t sB[2][BN * BKB];   // 2 x 32 KiB

    const int tid   = threadIdx.x;
    const int wave  = tid >> 6;
    const int lane  = tid & 63;
    const int l31   = lane & 31;
    const int lhalf = lane >> 5;        // 0/1
    const int rot   = l31 & 7;          // read-side swizzle rotation

    const int bm = blockIdx.y * BM;
    const int bn = blockIdx.x * BN;
    const int wm = (wave >> 2) * 128;   // 2 M-waves
    const int wn = (wave & 3) * 64;     // 4 N-waves

    i32x16 acc[4][2];
#pragma unroll
    for (int q = 0; q < 4; ++q)
#pragma unroll
        for (int n = 0; n < 2; ++n)
#pragma unroll
            for (int r = 0; r < 16; ++r) acc[q][n][r] = 0;

    // --- staging source pointers (inverse-swizzled chunk per thread) ---
    // load l of {0..3}: row = l*64 + tid/8, phys_chunk = tid&7,
    // log_chunk = (tid&7) ^ ((tid>>3)&7)  -> l-independent source offset.
    const int srow = tid >> 3;
    const int soff = (((tid & 7) ^ ((tid >> 3) & 7)) << 4);
    const int8_t* aS = A + (size_t)(bm + srow) * K + soff;
    const int8_t* bS = B + (size_t)(bn + srow) * K + soff;
    const size_t rstep = (size_t)64 * K;      // 64 rows per load round

    const int NT = K / BKB;

#define STAGE4(SRC, DST)                                                     \
    {                                                                        \
        _Pragma("unroll")                                                    \
        for (int l = 0; l < 4; ++l)                                          \
            __builtin_amdgcn_global_load_lds(                                \
                (const __attribute__((address_space(1))) void*)((SRC) + l * rstep), \
                (__attribute__((address_space(3))) void*)((DST) + l * 8192 + tid * 16), \
                16, 0, 0);                                                   \
    }

    // --- prologue: stage tile 0 into buffer 0 ---
    STAGE4(aS, &sA[0][0]);
    STAGE4(bS, &sB[0][0]);
    asm volatile("s_waitcnt vmcnt(0)" ::: "memory");
    __builtin_amdgcn_s_barrier();
    asm volatile("" ::: "memory");

    for (int t = 0; t < NT; ++t) {
        const int cur = t & 1;
        const int8_t* cA = &sA[cur][0];
        const int8_t* cB = &sB[cur][0];
        int8_t* nA = &sA[cur ^ 1][0];
        int8_t* nB = &sB[cur ^ 1][0];
        const size_t knext = (size_t)(t + 1) * BKB;
        const bool pf = (t + 1 < NT);   // uniform

        // B-frags for the whole tile (8 x ds_read_b128), register-cached
        i32x4 bf[2][4];
#pragma unroll
        for (int n = 0; n < 2; ++n)
#pragma unroll
            for (int ks = 0; ks < 4; ++ks) {
                const int row = wn + n * 32 + l31;
                bf[n][ks] = *(const i32x4*)(cB + row * BKB +
                                            ((((ks << 1) | lhalf) ^ rot) << 4));
            }

#pragma unroll
        for (int q = 0; q < 4; ++q) {
            // A-frags for M-tile q (4 x ds_read_b128)
            i32x4 af[4];
#pragma unroll
            for (int ks = 0; ks < 4; ++ks) {
                const int row = wm + q * 32 + l31;
                af[ks] = *(const i32x4*)(cA + row * BKB +
                                         ((((ks << 1) | lhalf) ^ rot) << 4));
            }

            // prefetch next tile early: A in phase 0, B in phase 1;
            // loads fly under the remaining phases' MFMA.
            if (q == 0 && pf) STAGE4(aS + knext, nA);
            if (q == 1 && pf) STAGE4(bS + knext, nB);

            // 8 MFMA: M-tile q x 2 N-tiles x 4 k-slices
#pragma unroll
            for (int n = 0; n < 2; ++n)
#pragma unroll
                for (int ks = 0; ks < 4; ++ks)
                    acc[q][n] = __builtin_amdgcn_mfma_i32_32x32x32_i8(
                        af[ks], bf[n][ks], acc[q][n], 0, 0, 0);
        }

        // tile boundary: drain this tile's prefetch, sync buffers
        asm volatile("s_waitcnt vmcnt(0)" ::: "memory");
        __builtin_amdgcn_s_barrier();
        asm volatile("" ::: "memory");
    }
#undef STAGE4

    // Epilogue: out = fp32( bf16( bf16(acc*xs*ws) + bf16(bias) ) )
#pragma unroll
    for (int n = 0; n < 2; ++n) {
        const int col = bn + wn + n * 32 + l31;
        const float wsv = ws[col];
        const float bsv = __bfloat162float(__float2bfloat16(bias[col]));
#pragma unroll
        for (int q = 0; q < 4; ++q) {
            const int rowbase = bm + wm + q * 32 + 4 * lhalf;
#pragma unroll
            for (int r = 0; r < 16; ++r) {
                const int row = rowbase + (r & 3) + 8 * (r >> 2);
                const float v = (float)acc[q][n][r] * xs[row] * wsv;
                const float vb = __bfloat162float(__float2bfloat16(v));
                const float res = __bfloat162float(__float2bfloat16(vb + bsv));
                out[(size_t)row * N + col] = res;
            }
        }
    }
}

// ---------------------------------------------------------------------------
extern "C" void kernel_launch(void* const* d_in, const int* in_sizes, int n_in,
                              void* d_out, int out_size, void* d_ws, size_t ws_size,
                              hipStream_t stream)
{
    const float* x    = (const float*)d_in[0];   // [B,S,K] fp32
    const float* wfp  = (const float*)d_in[1];   // [N,K] fp32
    const float* bias = (const float*)d_in[2];   // [N] fp32
    float* out = (float*)d_out;                  // [M,N] fp32

    const int N = in_sizes[2];
    const int K = in_sizes[1] / N;
    const int M = in_sizes[0] / K;

    // workspace layout: w_i8[N*K] | x_i8[M*K] | w_scales[N] | x_scales[M]
    int8_t* w_i8 = (int8_t*)d_ws;
    int8_t* x_i8 = w_i8 + (size_t)N * K;
    float* w_scales = (float*)(x_i8 + (size_t)M * K);
    float* x_scales = w_scales + N;

    const int nrows = N + M;                     // one wave per row
    const int nblocks = (nrows + 3) / 4;         // 4 waves / 256-thread block
    quant_rows_wave<<<nblocks, 256, 0, stream>>>(wfp, x, w_i8, x_i8,
                                                 w_scales, x_scales,
                                                 N, nrows, K);

    dim3 grid(N / BN, M / BM);
    gemm_i8_256<<<grid, 512, 0, stream>>>(x_i8, w_i8, x_scales, w_scales,
                                          bias, out, M, N, K);
}